// Round 7
// baseline (100.015 us; speedup 1.0000x reference)
//
#include <hip/hip_runtime.h>
#include <hip/hip_bf16.h>
#include <stdint.h>

#define NROWS 4096
#define DIMS  2048
#define BM    256
#define BK    64
#define NTILES (DIMS / BK)   // 32
#define NTB   (NROWS / BM)   // 16 -> 256 blocks
#define MARGIN_F 0.3f

typedef __attribute__((ext_vector_type(8))) short bf16x8;
typedef __attribute__((ext_vector_type(4))) float f32x4;
typedef __attribute__((ext_vector_type(4))) unsigned short us4;

__device__ inline unsigned short f2bf(float x) {
  union { float f; unsigned int u; } c; c.f = x;
  unsigned int lsb = (c.u >> 16) & 1u;
  c.u += 0x7fffu + lsb;               // round-to-nearest-even
  return (unsigned short)(c.u >> 16);
}

__device__ inline void atomicMaxF(float* addr, float v) {
  if (v >= 0.f) atomicMax((int*)addr, __float_as_int(v));
  else          atomicMin((unsigned int*)addr, __float_as_uint(v));
}
__device__ inline void atomicMinF(float* addr, float v) {
  if (v >= 0.f) atomicMin((int*)addr, __float_as_int(v));
  else          atomicMax((unsigned int*)addr, __float_as_uint(v));
}

__device__ inline void load_lds16(const void* g, void* l) {
  __builtin_amdgcn_global_load_lds(
      (const __attribute__((address_space(1))) void*)(g),
      (__attribute__((address_space(3))) void*)(l), 16, 0, 0);
}

// ---------------- normalize rows to bf16 + init dap/dan ----------------
__global__ __launch_bounds__(256) void norm_kernel(const float* __restrict__ in,
                                                   short* __restrict__ l2,
                                                   float* __restrict__ dap,
                                                   float* __restrict__ dan) {
  int row = blockIdx.x;
  int t = threadIdx.x;
  const float4* rin = (const float4*)(in + (size_t)row * DIMS);
  float4 v0 = rin[t];
  float4 v1 = rin[t + 256];
  float ss = v0.x*v0.x + v0.y*v0.y + v0.z*v0.z + v0.w*v0.w
           + v1.x*v1.x + v1.y*v1.y + v1.z*v1.z + v1.w*v1.w;
  #pragma unroll
  for (int s = 1; s < 64; s <<= 1) ss += __shfl_xor(ss, s);
  __shared__ float wsum[4];
  if ((t & 63) == 0) wsum[t >> 6] = ss;
  __syncthreads();
  float tot = wsum[0] + wsum[1] + wsum[2] + wsum[3];
  float rn = 1.0f / sqrtf(tot);
  short* orow = l2 + (size_t)row * DIMS;
  us4 o0, o1;
  o0.x = f2bf(v0.x * rn); o0.y = f2bf(v0.y * rn);
  o0.z = f2bf(v0.z * rn); o0.w = f2bf(v0.w * rn);
  o1.x = f2bf(v1.x * rn); o1.y = f2bf(v1.y * rn);
  o1.z = f2bf(v1.z * rn); o1.w = f2bf(v1.w * rn);
  *(us4*)(orow + 4 * t) = o0;
  *(us4*)(orow + 4 * t + 1024) = o1;
  if (t == 0) { dap[row] = -__builtin_inff(); dan[row] = __builtin_inff(); }
}

// ---------------- fused GEMM (G = L . L^T) + masked row max/min ----------------
// Faithful m201 8-phase discipline (4 phases per K-tile, 2 tiles per unrolled
// iter): each phase = {stage 1 half-tile; [P1/P3: vmcnt(6) gate]; s_barrier;
// ds_read this phase's fragments (8 or 4 x b128); lgkmcnt(0); setprio(1);
// 16 MFMA; setprio(0)}. Gates drain exactly the 2 half-tiles the following
// reads need (staged 3-4 phases earlier); 6 loads always in flight.
// Phase->quadrant map: P1=(m0-3,ks0) P2=(m4-7,ks0) P3=(m0-3,ks1) P4=(m4-7,ks1);
// b-frags (all n) read at P1/P3, reused at P2/P4. 24 b128 reads/tile (minimal).
// LDS per set per operand: [2 ks][256 rows][32 k] bf16, chunk-swizzled
// q = c ^ ((row>>1)&3); staging linear dest + pre-swizzled coalesced source.
__global__ __launch_bounds__(512, 2) void gemm_reduce_kernel(
    const short* __restrict__ l2, const int* __restrict__ tgt,
    float* __restrict__ dap, float* __restrict__ dan) {
  __shared__ __attribute__((aligned(16))) short ldsA[2][16384];  // 2 sets x 32 KB
  __shared__ __attribute__((aligned(16))) short ldsB[2][16384];

  // XCD-chunked bijective swizzle (256 blocks, 8 XCDs -> 32 contiguous per XCD)
  int c = blockIdx.x;
  int swz = (c & 7) * 32 + (c >> 3);
  int bi = swz >> 4, bj = swz & 15;

  int tid = threadIdx.x;
  int lane = tid & 63, w = tid >> 6;
  int wr = w >> 2;        // 0..1  (M half: 128 rows)
  int nc = w & 3;         // 0..3  (N quarter: 64 cols)

  f32x4 acc[8][4];
  #pragma unroll
  for (int m = 0; m < 8; m++)
    #pragma unroll
    for (int n = 0; n < 4; n++) acc[m][n] = (f32x4){0.f, 0.f, 0.f, 0.f};

  // --- staging source (verified r4-r6: coalesced, pre-swizzled) ---
  int srow = tid >> 2;                               // 0..127
  int qq = (tid & 3) ^ ((tid >> 3) & 3);
  const short* gA = l2 + ((size_t)(bi * BM + srow)) * DIMS + qq * 8;
  const short* gB = l2 + ((size_t)(bj * BM + srow)) * DIMS + qq * 8;

  // --- fragment read offsets (verified r4-r6) ---
  int laneq = lane & 15, g = lane >> 4;
  int fc = (g ^ ((laneq >> 1) & 3)) * 8;             // swizzled chunk slot
  int aOff = (wr * 128 + laneq) * 32 + fc;
  int bOff = (nc * 64 + laneq) * 32 + fc;

  bf16x8 aU[4], aV[4], bR[4];

  #define STAGE_A(T, KS, P)                                                   \
    do {                                                                      \
      load_lds16(gA + (size_t)(T) * 64 + (KS) * 32,                           \
                 &ldsA[P][(KS) * 8192 + w * 512]);                            \
      load_lds16(gA + 128 * (size_t)DIMS + (size_t)(T) * 64 + (KS) * 32,      \
                 &ldsA[P][(KS) * 8192 + 4096 + w * 512]);                     \
    } while (0)
  #define STAGE_B(T, KS, P)                                                   \
    do {                                                                      \
      load_lds16(gB + (size_t)(T) * 64 + (KS) * 32,                           \
                 &ldsB[P][(KS) * 8192 + w * 512]);                            \
      load_lds16(gB + 128 * (size_t)DIMS + (size_t)(T) * 64 + (KS) * 32,      \
                 &ldsB[P][(KS) * 8192 + 4096 + w * 512]);                     \
    } while (0)

  #define READ_A(DST, MO, KS, P)                                              \
    _Pragma("unroll")                                                         \
    for (int m = 0; m < 4; m++)                                               \
      DST[m] = *(const bf16x8*)&ldsA[P][(KS) * 8192 + aOff + ((MO) + m) * 512];
  #define READ_B(DST, KS, P)                                                  \
    _Pragma("unroll")                                                         \
    for (int n = 0; n < 4; n++)                                               \
      DST[n] = *(const bf16x8*)&ldsB[P][(KS) * 8192 + bOff + n * 512];

  #define MFMA16(MO, AR, BR)                                                  \
    __builtin_amdgcn_s_setprio(1);                                            \
    _Pragma("unroll")                                                         \
    for (int m = 0; m < 4; m++)                                               \
      _Pragma("unroll")                                                       \
      for (int n = 0; n < 4; n++)                                             \
        acc[(MO) + m][n] = __builtin_amdgcn_mfma_f32_16x16x32_bf16(           \
            AR[m], BR[n], acc[(MO) + m][n], 0, 0, 0);                         \
    __builtin_amdgcn_s_setprio(0);

  #define SB __builtin_amdgcn_sched_barrier(0);
  #define LGKM0                                                               \
    asm volatile("s_waitcnt lgkmcnt(0)" ::: "memory");                        \
    SB
  #define VM6                                                                 \
    asm volatile("s_waitcnt vmcnt(6)" ::: "memory");                          \
    SB
  #define BAR __builtin_amdgcn_s_barrier(); SB

  // Per tile t (set P=t&1): compute from set P, stage tile TN into set P^1.
  #define ITER(P, TN)                                                         \
    do {                                                                      \
      /* P1: (m0-3, ks0) */                                                   \
      STAGE_A(TN, 0, (P) ^ 1);                                                \
      VM6                                                                     \
      BAR                                                                     \
      READ_A(aU, 0, 0, P)                                                     \
      READ_B(bR, 0, P)                                                        \
      LGKM0                                                                   \
      MFMA16(0, aU, bR)                                                       \
      /* P2: (m4-7, ks0) */                                                   \
      STAGE_B(TN, 0, (P) ^ 1);                                                \
      BAR                                                                     \
      READ_A(aV, 4, 0, P)                                                     \
      LGKM0                                                                   \
      MFMA16(4, aV, bR)                                                       \
      /* P3: (m0-3, ks1) */                                                   \
      STAGE_A(TN, 1, (P) ^ 1);                                                \
      VM6                                                                     \
      BAR                                                                     \
      READ_A(aU, 0, 1, P)                                                     \
      READ_B(bR, 1, P)                                                        \
      LGKM0                                                                   \
      MFMA16(0, aU, bR)                                                       \
      /* P4: (m4-7, ks1) */                                                   \
      STAGE_B(TN, 1, (P) ^ 1);                                                \
      BAR                                                                     \
      READ_A(aV, 4, 1, P)                                                     \
      LGKM0                                                                   \
      MFMA16(4, aV, bR)                                                       \
    } while (0)

  // prologue: stage tile0's 4 half-tiles into set0 (oldest-first order
  // matches the steady-state vmcnt(6) drain accounting)
  STAGE_A(0, 0, 0);
  STAGE_B(0, 0, 0);
  STAGE_A(0, 1, 0);
  STAGE_B(0, 1, 0);

  #pragma unroll 1
  for (int kt = 0; kt < NTILES; kt += 2) {
    ITER(0, kt + 1);                                   // kt+1 <= 31
    ITER(1, (kt + 2 < NTILES) ? kt + 2 : NTILES - 1);  // last: benign re-stage
  }

  // ---- fused masked reduction ----
  // acc[m][n][r] = G[bi*256 + wr*128 + m*16 + (lane>>4)*4 + r]
  //                 [bj*256 + nc*64  + n*16 + (lane&15)]
  int tcol[4];
  #pragma unroll
  for (int n = 0; n < 4; n++) tcol[n] = tgt[bj * BM + nc * 64 + n * 16 + (lane & 15)];
  int rbase = bi * BM + wr * 128 + (lane >> 4) * 4;

  #pragma unroll
  for (int m = 0; m < 8; m++) {
    #pragma unroll
    for (int r = 0; r < 4; r++) {
      int grow = rbase + m * 16 + r;
      int trow = tgt[grow];
      float ap = -__builtin_inff(), an = __builtin_inff();
      #pragma unroll
      for (int n = 0; n < 4; n++) {
        float d = -acc[m][n][r];
        bool same = (trow == tcol[n]);
        ap = same ? fmaxf(ap, d) : ap;
        an = same ? an : fminf(an, d);
      }
      #pragma unroll
      for (int s = 1; s < 16; s <<= 1) {
        ap = fmaxf(ap, __shfl_xor(ap, s));
        an = fminf(an, __shfl_xor(an, s));
      }
      if ((lane & 15) == 0) {
        atomicMaxF(&dap[grow], ap);
        atomicMinF(&dan[grow], an);
      }
    }
  }
  #undef STAGE_A
  #undef STAGE_B
  #undef READ_A
  #undef READ_B
  #undef MFMA16
  #undef SB
  #undef LGKM0
  #undef VM6
  #undef BAR
  #undef ITER
}

// ---------------- final loss ----------------
__global__ __launch_bounds__(256) void loss_kernel(const float* __restrict__ dap,
                                                   const float* __restrict__ dan,
                                                   float* __restrict__ out) {
  int t = threadIdx.x;
  float s = 0.f;
  for (int i = t; i < NROWS; i += 256) {
    float v = dap[i] - dan[i] + MARGIN_F;
    s += v > 0.f ? v : 0.f;
  }
  #pragma unroll
  for (int sh = 1; sh < 64; sh <<= 1) s += __shfl_xor(s, sh);
  __shared__ float ws[4];
  if ((t & 63) == 0) ws[t >> 6] = s;
  __syncthreads();
  if (t == 0) out[0] = (ws[0] + ws[1] + ws[2] + ws[3]) * (1.0f / (float)NROWS);
}

extern "C" void kernel_launch(void* const* d_in, const int* in_sizes, int n_in,
                              void* d_out, int out_size, void* d_ws, size_t ws_size,
                              hipStream_t stream) {
  const float* inputs = (const float*)d_in[0];
  const int* targets = (const int*)d_in[1];
  short* l2 = (short*)d_ws;
  float* dap = (float*)((char*)d_ws + (size_t)NROWS * DIMS * 2);
  float* dan = dap + NROWS;
  float* out = (float*)d_out;

  hipLaunchKernelGGL(norm_kernel, dim3(NROWS), dim3(256), 0, stream,
                     inputs, l2, dap, dan);
  hipLaunchKernelGGL(gemm_reduce_kernel, dim3(NTB * NTB), dim3(512), 0, stream,
                     l2, targets, dap, dan);
  hipLaunchKernelGGL(loss_kernel, dim3(1), dim3(256), 0, stream, dap, dan, out);
}